// Round 4
// baseline (716.037 us; speedup 1.0000x reference)
//
#include <hip/hip_runtime.h>

#define BB   2
#define NN   50000
#define EE   800000
#define INCH 64
#define C1   16
#define C2   32
#define NB   (BB*NN)
#define NBUK 782          // ceil(NN/64) buckets of 64 dsts
#define APB  4096         // edges staged per block in bucket pass

// workspace layout (float offsets). xs/aggr/dot* are batch-INTERLEAVED:
// xs1[node][b][C1], dotk1[node*2+b], etc.
#define OFF_XS1   0
#define OFF_AGGR1 (OFF_XS1   + NB*C1)
#define OFF_DOTK1 (OFF_AGGR1 + NB*C1)
#define OFF_DOTQ1 (OFF_DOTK1 + NB)
#define OFF_XS2   (OFF_DOTQ1 + NB)
#define OFF_AGGR2 (OFF_XS2   + NB*C2)
#define OFF_DOTK2 (OFF_AGGR2 + NB*C2)
#define OFF_DOTQ2 (OFF_DOTK2 + NB)
#define OFF_COMBO (OFF_DOTQ2 + NB)
#define OFF_CNT   (OFF_COMBO + 128)          // 2*NBUK ints
#define OFF_BASE0 (OFF_CNT   + 2*NBUK)       // NBUK+1
#define OFF_BASE1 (OFF_BASE0 + NBUK + 1)
#define OFF_CUR0  (OFF_BASE1 + NBUK + 1)
#define OFF_CUR1  (OFF_CUR0  + NBUK)
#define OFF_PK0   (((OFF_CUR1 + NBUK) + 1) & ~1)   // 8B aligned
#define OFF_PK1   (OFF_PK0   + 2*EE)
// combo: [0:16] kv1, [16:32] qv1, [32:64] kv2, [64:96] qv2, [96] ec1, [97] ec2

__device__ __forceinline__ float sigmoidf(float x) {
    return 1.0f / (1.0f + __expf(-x));
}

// ---------------- tiny combo precompute --------------------------------------
__global__ void k_combos(const float* __restrict__ key1, const float* __restrict__ query1,
                         const float* __restrict__ we1,  const float* __restrict__ aw1,
                         const float* __restrict__ key2, const float* __restrict__ query2,
                         const float* __restrict__ we2,  const float* __restrict__ aw2,
                         float* __restrict__ combo) {
    int c = threadIdx.x;
    if (c < C1) {
        float kv = 0.f, qv = 0.f;
        for (int j = 0; j < C1; ++j) {
            kv += key1[c*C1+j]   * aw1[j];
            qv += query1[c*C1+j] * aw1[C1+j];
        }
        combo[c] = kv; combo[16+c] = qv;
    }
    if (c < C2) {
        float kv = 0.f, qv = 0.f;
        for (int j = 0; j < C2; ++j) {
            kv += key2[c*C2+j]   * aw2[j];
            qv += query2[c*C2+j] * aw2[C2+j];
        }
        combo[32+c] = kv; combo[64+c] = qv;
    }
    if (c == 0) {
        float e1 = 0.f, e2 = 0.f;
        for (int j = 0; j < C1; ++j) e1 += we1[j] * aw1[2*C1+j];
        for (int j = 0; j < C2; ++j) e2 += we2[j] * aw2[2*C2+j];
        combo[96] = e1; combo[97] = e2;
    }
}

// ---------------- coarse dst-bucket histogram, both layers -------------------
__global__ __launch_bounds__(1024) void k_bhist(
        const int* __restrict__ ei0, const int* __restrict__ ei1,
        int* __restrict__ cnt) {    // [0:NBUK) layer0, [NBUK:2NBUK) layer1
    __shared__ int h[2*NBUK];
    int t = threadIdx.x;
    for (int i = t; i < 2*NBUK; i += 1024) h[i] = 0;
    __syncthreads();
    int base = blockIdx.x * 8192;
#pragma unroll
    for (int i = 0; i < 8; ++i) {
        int idx = base + t + i*1024;
        if (idx < EE)          atomicAdd(&h[ei0[EE + idx] >> 6], 1);
        else if (idx < 2*EE)   atomicAdd(&h[NBUK + (ei1[idx] >> 6)], 1);  // ei1[EE+(idx-EE)]
    }
    __syncthreads();
    for (int i = t; i < 2*NBUK; i += 1024) {
        int v = h[i];
        if (v) atomicAdd(&cnt[i], v);
    }
}

// ---------------- scan of bucket counts -> base & cursor ---------------------
__global__ __launch_bounds__(1024) void k_bscan(
        const int* __restrict__ cnt, int* __restrict__ base0, int* __restrict__ base1,
        int* __restrict__ cur0, int* __restrict__ cur1) {
    __shared__ int s[1024];
    int layer = blockIdx.x;
    const int* c = cnt + layer*NBUK;
    int* base = layer ? base1 : base0;
    int* cur  = layer ? cur1  : cur0;
    int t = threadIdx.x;
    int v = (t < NBUK) ? c[t] : 0;
    s[t] = v;
    __syncthreads();
    for (int off = 1; off < 1024; off <<= 1) {
        int u = (t >= off) ? s[t - off] : 0;
        __syncthreads();
        s[t] += u;
        __syncthreads();
    }
    if (t < NBUK) {
        int ex = s[t] - v;
        base[t] = ex; cur[t] = ex;
    }
    if (t == 1023) base[NBUK] = s[t];
}

// ---------------- bucket pass: stage, block-sort, coalesced append -----------
__global__ __launch_bounds__(1024) void k_bucket(
        const int* __restrict__ ei, const float* __restrict__ ew,
        int* __restrict__ cur, int2* __restrict__ pk) {
    __shared__ int  hist[1024];
    __shared__ int  lbase[NBUK];
    __shared__ int  gbase[NBUK];
    __shared__ int  lcur[NBUK];
    __shared__ int2 stage[APB];       // 32 KB
    int t = threadIdx.x;
    int e0 = blockIdx.x * APB;
    int n  = EE - e0; if (n > APB) n = APB;
    int srcv[4]; int dstv[4]; float efv[4];
    hist[t] = 0;
    __syncthreads();
#pragma unroll
    for (int i = 0; i < 4; ++i) {
        int idx = e0 + t + i*1024;
        if (idx < EE) {
            srcv[i] = ei[idx];
            dstv[i] = ei[EE + idx];
            efv[i]  = ew[idx];
            atomicAdd(&hist[dstv[i] >> 6], 1);
        } else dstv[i] = -1;
    }
    __syncthreads();
    int cnt_t = hist[t];
    for (int off = 1; off < 1024; off <<= 1) {
        int v = (t >= off) ? hist[t - off] : 0;
        __syncthreads();
        hist[t] += v;
        __syncthreads();
    }
    if (t < NBUK) {
        int lb = hist[t] - cnt_t;
        lbase[t] = lb;
        lcur[t]  = lb;
        gbase[t] = (cnt_t > 0) ? atomicAdd(&cur[t], cnt_t) : 0;   // 1 per (block,bucket)
    }
    __syncthreads();
#pragma unroll
    for (int i = 0; i < 4; ++i) {
        if (dstv[i] >= 0) {
            int bk  = dstv[i] >> 6;
            int pos = atomicAdd(&lcur[bk], 1);     // LDS returning atomic (cheap)
            stage[pos] = make_int2(srcv[i] | ((dstv[i] & 63) << 16),
                                   __float_as_int(efv[i]));
        }
    }
    __syncthreads();
    // coalesced copy-out; hist[] holds inclusive scan for bucket lookup
    for (int p = t; p < n; p += 1024) {
        int lo = 0, hi = NBUK - 1;
        while (lo < hi) { int mid = (lo + hi) >> 1; if (hist[mid] > p) hi = mid; else lo = mid + 1; }
        pk[gbase[lo] + (p - lbase[lo])] = stage[p];
    }
}

// ---------------- layer 1: xs1 = X @ value1, interleaved out -----------------
__global__ __launch_bounds__(256) void k_value1(
        const float* __restrict__ X, const float* __restrict__ value1,
        const float* __restrict__ combo,
        float* __restrict__ xs1, float* __restrict__ dotk1, float* __restrict__ dotq1) {
    __shared__ float W[INCH*C1];
    __shared__ float KV[C1], QV[C1];
    int tid = threadIdx.x;
    for (int i = tid; i < INCH*C1; i += 256) W[i] = value1[i];
    if (tid < C1) { KV[tid] = combo[tid]; QV[tid] = combo[16+tid]; }
    __syncthreads();
    int bn = blockIdx.x * 256 + tid;
    if (bn >= NB) return;
    int bb = (bn >= NN) ? 1 : 0;
    int node = bn - bb*NN;
    int row = node*2 + bb;
    const float4* Xr = (const float4*)(X + (size_t)bn * INCH);
    float acc[C1];
#pragma unroll
    for (int j = 0; j < C1; ++j) acc[j] = 0.f;
#pragma unroll
    for (int v = 0; v < 16; ++v) {
        float4 p = Xr[v];
        float x4[4] = {p.x, p.y, p.z, p.w};
#pragma unroll
        for (int h = 0; h < 4; ++h) {
            int i = v*4 + h;
            float xv = x4[h];
#pragma unroll
            for (int j = 0; j < C1; ++j) acc[j] += xv * W[i*C1+j];
        }
    }
    float dk = 0.f, dq = 0.f;
#pragma unroll
    for (int j = 0; j < C1; ++j) { dk += acc[j]*KV[j]; dq += acc[j]*QV[j]; }
    float4* o = (float4*)(xs1 + (size_t)row * C1);
#pragma unroll
    for (int v = 0; v < 4; ++v)
        o[v] = make_float4(acc[4*v], acc[4*v+1], acc[4*v+2], acc[4*v+3]);
    dotk1[row] = dk; dotq1[row] = dq;
}

// ---------------- layer-1 aggregate: LDS accumulation per bucket -------------
__global__ __launch_bounds__(1024) void k_aggr1(
        const int* __restrict__ base, const int2* __restrict__ pk,
        const float* __restrict__ we, const float* __restrict__ ab,
        const float* __restrict__ combo,
        const float* __restrict__ xs, const float* __restrict__ dotk,
        const float* __restrict__ dotq, float* __restrict__ aggr) {
    __shared__ float acc[64*2*C1];
    __shared__ float dkS[64*2];
    int t = threadIdx.x;
    int b = blockIdx.x;
    int dst0 = b << 6;
    int ndst = NN - dst0; if (ndst > 64) ndst = 64;
    for (int i = t; i < 64*2*C1; i += 1024) acc[i] = 0.f;
    for (int i = t; i < ndst*2;  i += 1024) dkS[i] = dotk[dst0*2 + i];
    __syncthreads();
    int lane = t & 15, g = t >> 4;          // 64 groups of 16
    float wec = we[lane];
    float ec  = combo[96], abv = ab[0];
    int beg = base[b], end = base[b+1];
    for (int p = beg + g; p < end; p += 64) {
        int2 r = pk[p];
        int src = r.x & 0xFFFF;
        int dl  = (r.x >> 16) & 63;
        float ef = __int_as_float(r.y);
        float sig_e = sigmoidf(ef * wec);
        float eb    = ef * ec + abv;
        float2 dq = *(const float2*)(dotq + src*2);
        float xj0 = xs[src*2*C1 + lane];
        float xj1 = xs[src*2*C1 + C1 + lane];
        float dk0 = dkS[dl*2], dk1 = dkS[dl*2+1];
        atomicAdd(&acc[(dl*2+0)*C1 + lane], sigmoidf(dk0 + dq.x + eb) * xj0 * sig_e);
        atomicAdd(&acc[(dl*2+1)*C1 + lane], sigmoidf(dk1 + dq.y + eb) * xj1 * sig_e);
    }
    __syncthreads();
    for (int i = t; i < ndst*2*C1; i += 1024) aggr[dst0*2*C1 + i] = acc[i];
}

// ---------------- fused: update1 + leaky_relu + xs2 = X1 @ value2 ------------
__global__ __launch_bounds__(256) void k_update1(
        const float* __restrict__ cat_w, const float* __restrict__ cat_b,
        const float* __restrict__ value2, const float* __restrict__ combo,
        const float* __restrict__ xs1, const float* __restrict__ aggr1,
        float* __restrict__ xs2, float* __restrict__ dotk2, float* __restrict__ dotq2) {
    __shared__ float CW[2*C1*C1];
    __shared__ float CB[C1];
    __shared__ float V2[C1*C2];
    __shared__ float KV[C2], QV[C2];
    int tid = threadIdx.x;
    for (int i = tid; i < 2*C1*C1; i += 256) CW[i] = cat_w[i];
    for (int i = tid; i < C1*C2;   i += 256) V2[i] = value2[i];
    if (tid < C1) CB[tid] = cat_b[tid];
    if (tid < C2) { KV[tid] = combo[32+tid]; QV[tid] = combo[64+tid]; }
    __syncthreads();
    int bn = blockIdx.x * 256 + tid;
    if (bn >= NB) return;
    int bb = (bn >= NN) ? 1 : 0;
    int node = bn - bb*NN;
    int row = node*2 + bb;
    const float4* xr = (const float4*)(xs1   + (size_t)row * C1);
    const float4* ar = (const float4*)(aggr1 + (size_t)row * C1);
    float xd[C1], ag[C1];
#pragma unroll
    for (int v = 0; v < 4; ++v) {
        float4 a = xr[v], b = ar[v];
        xd[4*v]=a.x; xd[4*v+1]=a.y; xd[4*v+2]=a.z; xd[4*v+3]=a.w;
        ag[4*v]=b.x; ag[4*v+1]=b.y; ag[4*v+2]=b.z; ag[4*v+3]=b.w;
    }
    float x1[C1];
#pragma unroll
    for (int j = 0; j < C1; ++j) {
        float u = CB[j];
#pragma unroll
        for (int i = 0; i < C1; ++i) {
            u += xd[i] * CW[i*C1 + j];
            u += ag[i] * CW[(C1+i)*C1 + j];
        }
        float o = xd[j] + fmaxf(u, 0.f);
        x1[j] = (o > 0.f) ? o : 0.01f * o;       // leaky_relu
    }
    float o2[C2];
#pragma unroll
    for (int k = 0; k < C2; ++k) o2[k] = 0.f;
#pragma unroll
    for (int j = 0; j < C1; ++j) {
        float xv = x1[j];
#pragma unroll
        for (int k = 0; k < C2; ++k) o2[k] += xv * V2[j*C2 + k];
    }
    float dk = 0.f, dq = 0.f;
#pragma unroll
    for (int k = 0; k < C2; ++k) { dk += o2[k]*KV[k]; dq += o2[k]*QV[k]; }
    float4* o = (float4*)(xs2 + (size_t)row * C2);
#pragma unroll
    for (int v = 0; v < 8; ++v)
        o[v] = make_float4(o2[4*v], o2[4*v+1], o2[4*v+2], o2[4*v+3]);
    dotk2[row] = dk; dotq2[row] = dq;
}

// ---------------- layer-2 aggregate: LDS accumulation per bucket -------------
__global__ __launch_bounds__(1024) void k_aggr2(
        const int* __restrict__ base, const int2* __restrict__ pk,
        const float* __restrict__ we, const float* __restrict__ ab,
        const float* __restrict__ combo,
        const float* __restrict__ xs, const float* __restrict__ dotk,
        const float* __restrict__ dotq, float* __restrict__ aggr) {
    __shared__ float acc[64*2*C2];          // 16 KB
    __shared__ float dkS[64*2];
    int t = threadIdx.x;
    int b = blockIdx.x;
    int dst0 = b << 6;
    int ndst = NN - dst0; if (ndst > 64) ndst = 64;
    for (int i = t; i < 64*2*C2; i += 1024) acc[i] = 0.f;
    for (int i = t; i < ndst*2;  i += 1024) dkS[i] = dotk[dst0*2 + i];
    __syncthreads();
    int lane = t & 31, g = t >> 5;          // 32 groups of 32
    float wec = we[lane];
    float ec  = combo[97], abv = ab[0];
    int beg = base[b], end = base[b+1];
    for (int p = beg + g; p < end; p += 32) {
        int2 r = pk[p];
        int src = r.x & 0xFFFF;
        int dl  = (r.x >> 16) & 63;
        float ef = __int_as_float(r.y);
        float sig_e = sigmoidf(ef * wec);
        float eb    = ef * ec + abv;
        float2 dq = *(const float2*)(dotq + src*2);
        float xj0 = xs[src*2*C2 + lane];
        float xj1 = xs[src*2*C2 + C2 + lane];
        float dk0 = dkS[dl*2], dk1 = dkS[dl*2+1];
        atomicAdd(&acc[(dl*2+0)*C2 + lane], sigmoidf(dk0 + dq.x + eb) * xj0 * sig_e);
        atomicAdd(&acc[(dl*2+1)*C2 + lane], sigmoidf(dk1 + dq.y + eb) * xj1 * sig_e);
    }
    __syncthreads();
    for (int i = t; i < ndst*2*C2; i += 1024) aggr[dst0*2*C2 + i] = acc[i];
}

// ---------------- final: update2 -> fp32 out ---------------------------------
__global__ __launch_bounds__(256) void k_update2(
        const float* __restrict__ cat_w, const float* __restrict__ cat_b,
        const float* __restrict__ xs2, const float* __restrict__ aggr2,
        float* __restrict__ out) {
    __shared__ float CW[2*C2*C2];
    __shared__ float CB[C2];
    int tid = threadIdx.x;
    for (int i = tid; i < 2*C2*C2; i += 256) CW[i] = cat_w[i];
    if (tid < C2) CB[tid] = cat_b[tid];
    __syncthreads();
    int bn = blockIdx.x * 256 + tid;
    if (bn >= NB) return;
    int bb = (bn >= NN) ? 1 : 0;
    int node = bn - bb*NN;
    int row = node*2 + bb;
    const float4* xr = (const float4*)(xs2   + (size_t)row * C2);
    const float4* ar = (const float4*)(aggr2 + (size_t)row * C2);
    float xd[C2], ag[C2];
#pragma unroll
    for (int v = 0; v < 8; ++v) {
        float4 a = xr[v], b = ar[v];
        xd[4*v]=a.x; xd[4*v+1]=a.y; xd[4*v+2]=a.z; xd[4*v+3]=a.w;
        ag[4*v]=b.x; ag[4*v+1]=b.y; ag[4*v+2]=b.z; ag[4*v+3]=b.w;
    }
    float o[C2];
#pragma unroll
    for (int k = 0; k < C2; ++k) {
        float u = CB[k];
#pragma unroll
        for (int i = 0; i < C2; ++i) {
            u += xd[i] * CW[i*C2 + k];
            u += ag[i] * CW[(C2+i)*C2 + k];
        }
        o[k] = xd[k] + fmaxf(u, 0.f);
    }
    float4* dst = (float4*)(out + (size_t)bn * C2);
#pragma unroll
    for (int v = 0; v < 8; ++v)
        dst[v] = make_float4(o[4*v], o[4*v+1], o[4*v+2], o[4*v+3]);
}

extern "C" void kernel_launch(void* const* d_in, const int* in_sizes, int n_in,
                              void* d_out, int out_size, void* d_ws, size_t ws_size,
                              hipStream_t stream) {
    const float* X      = (const float*)d_in[0];
    const int*   ei0    = (const int*)d_in[1];
    const int*   ei1    = (const int*)d_in[2];
    const float* ew0    = (const float*)d_in[3];
    const float* ew1    = (const float*)d_in[4];
    // d_in[5], d_in[6]: res_n_id0/1 == arange(N) -> identity gather, unused
    const float* value1 = (const float*)d_in[7];
    const float* key1   = (const float*)d_in[8];
    const float* query1 = (const float*)d_in[9];
    const float* we1    = (const float*)d_in[10];
    const float* aw1    = (const float*)d_in[11];
    const float* ab1    = (const float*)d_in[12];
    const float* cw1    = (const float*)d_in[13];
    const float* cb1    = (const float*)d_in[14];
    const float* value2 = (const float*)d_in[15];
    const float* key2   = (const float*)d_in[16];
    const float* query2 = (const float*)d_in[17];
    const float* we2    = (const float*)d_in[18];
    const float* aw2    = (const float*)d_in[19];
    const float* ab2    = (const float*)d_in[20];
    const float* cw2    = (const float*)d_in[21];
    const float* cb2    = (const float*)d_in[22];
    float* ws  = (float*)d_ws;
    float* out = (float*)d_out;

    int*  cnt   = (int*)(ws + OFF_CNT);
    int*  base0 = (int*)(ws + OFF_BASE0);
    int*  base1 = (int*)(ws + OFF_BASE1);
    int*  cur0  = (int*)(ws + OFF_CUR0);
    int*  cur1  = (int*)(ws + OFF_CUR1);
    int2* pk0   = (int2*)(ws + OFF_PK0);
    int2* pk1   = (int2*)(ws + OFF_PK1);

    hipMemsetAsync(cnt, 0, (size_t)2 * NBUK * sizeof(int), stream);

    k_combos<<<1, 64, 0, stream>>>(key1, query1, we1, aw1, key2, query2, we2, aw2,
                                   ws + OFF_COMBO);
    k_bhist<<<(2*EE + 8191)/8192, 1024, 0, stream>>>(ei0, ei1, cnt);
    k_bscan<<<2, 1024, 0, stream>>>(cnt, base0, base1, cur0, cur1);
    k_bucket<<<(EE + APB - 1)/APB, 1024, 0, stream>>>(ei0, ew0, cur0, pk0);
    k_bucket<<<(EE + APB - 1)/APB, 1024, 0, stream>>>(ei1, ew1, cur1, pk1);
    k_value1<<<(NB+255)/256, 256, 0, stream>>>(X, value1, ws + OFF_COMBO,
                                               ws + OFF_XS1, ws + OFF_DOTK1, ws + OFF_DOTQ1);
    k_aggr1<<<NBUK, 1024, 0, stream>>>(base0, pk0, we1, ab1, ws + OFF_COMBO,
                                       ws + OFF_XS1, ws + OFF_DOTK1, ws + OFF_DOTQ1,
                                       ws + OFF_AGGR1);
    k_update1<<<(NB+255)/256, 256, 0, stream>>>(cw1, cb1, value2, ws + OFF_COMBO,
                                                ws + OFF_XS1, ws + OFF_AGGR1,
                                                ws + OFF_XS2, ws + OFF_DOTK2, ws + OFF_DOTQ2);
    k_aggr2<<<NBUK, 1024, 0, stream>>>(base1, pk1, we2, ab2, ws + OFF_COMBO,
                                       ws + OFF_XS2, ws + OFF_DOTK2, ws + OFF_DOTQ2,
                                       ws + OFF_AGGR2);
    k_update2<<<(NB+255)/256, 256, 0, stream>>>(cw2, cb2, ws + OFF_XS2, ws + OFF_AGGR2, out);
}

// Round 6
// 328.629 us; speedup vs baseline: 2.1789x; 2.1789x over previous
//
#include <hip/hip_runtime.h>
#include <hip/hip_fp16.h>

#define BB   2
#define NN   50000
#define EE   800000
#define INCH 64
#define C1   16
#define C2   32
#define NB   (BB*NN)

// workspace layout (float-unit offsets; regions sized generously as if f32).
// xs/aggr are __half2[node][c] with .x=batch0,.y=batch1. dot*[node][b] f32.
#define OFF_XS1   0
#define OFF_XS2   (OFF_XS1   + NB*C1)
#define OFF_AGGR1 (OFF_XS2   + NB*C2)
#define OFF_AGGR2 (OFF_AGGR1 + NB*C1)
#define OFF_DOTK1 (OFF_AGGR2 + NB*C2)
#define OFF_DOTQ1 (OFF_DOTK1 + NB)
#define OFF_DOTK2 (OFF_DOTQ1 + NB)
#define OFF_DOTQ2 (OFF_DOTK2 + NB)
#define OFF_COMBO (OFF_DOTQ2 + NB)
// combo: [0:16] kv1, [16:32] qv1, [32:64] kv2, [64:96] qv2, [96] ec1, [97] ec2

__device__ __forceinline__ float sigmoidf(float x) {
    return 1.0f / (1.0f + __expf(-x));
}

// packed 2xfp16 atomic add, device scope (sc1), fire-and-forget.
// global_atomic_pk_add_f16 is real CDNA ISA (unlike pk_add_f32 — R5 lesson).
__device__ __forceinline__ void atomic_pk_add_f16(__half2* addr, __half2 v) {
    unsigned int bits = *reinterpret_cast<unsigned int*>(&v);
    asm volatile("global_atomic_pk_add_f16 %0, %1, off sc1"
                 :: "v"(addr), "v"(bits) : "memory");
}

// ---------------- tiny combo precompute --------------------------------------
__global__ void k_combos(const float* __restrict__ key1, const float* __restrict__ query1,
                         const float* __restrict__ we1,  const float* __restrict__ aw1,
                         const float* __restrict__ key2, const float* __restrict__ query2,
                         const float* __restrict__ we2,  const float* __restrict__ aw2,
                         float* __restrict__ combo) {
    int c = threadIdx.x;
    if (c < C1) {
        float kv = 0.f, qv = 0.f;
        for (int j = 0; j < C1; ++j) {
            kv += key1[c*C1+j]   * aw1[j];
            qv += query1[c*C1+j] * aw1[C1+j];
        }
        combo[c] = kv; combo[16+c] = qv;
    }
    if (c < C2) {
        float kv = 0.f, qv = 0.f;
        for (int j = 0; j < C2; ++j) {
            kv += key2[c*C2+j]   * aw2[j];
            qv += query2[c*C2+j] * aw2[C2+j];
        }
        combo[32+c] = kv; combo[64+c] = qv;
    }
    if (c == 0) {
        float e1 = 0.f, e2 = 0.f;
        for (int j = 0; j < C1; ++j) e1 += we1[j] * aw1[2*C1+j];
        for (int j = 0; j < C2; ++j) e2 += we2[j] * aw2[2*C2+j];
        combo[96] = e1; combo[97] = e2;
    }
}

// ---------------- layer 1: xs1 = X @ value1 (half2-packed out) ---------------
__global__ __launch_bounds__(256) void k_value1(
        const float* __restrict__ X, const float* __restrict__ value1,
        const float* __restrict__ combo,
        __half* __restrict__ xs1h, float* __restrict__ dotk1, float* __restrict__ dotq1) {
    __shared__ float W[INCH*C1];
    __shared__ float KV[C1], QV[C1];
    int tid = threadIdx.x;
    for (int i = tid; i < INCH*C1; i += 256) W[i] = value1[i];
    if (tid < C1) { KV[tid] = combo[tid]; QV[tid] = combo[16+tid]; }
    __syncthreads();
    int bn = blockIdx.x * 256 + tid;
    if (bn >= NB) return;
    int b = (bn >= NN) ? 1 : 0;
    int node = bn - b*NN;
    const float4* Xr = (const float4*)(X + (size_t)bn * INCH);
    float acc[C1];
#pragma unroll
    for (int j = 0; j < C1; ++j) acc[j] = 0.f;
#pragma unroll
    for (int v = 0; v < 16; ++v) {
        float4 p = Xr[v];
        float x4[4] = {p.x, p.y, p.z, p.w};
#pragma unroll
        for (int h = 0; h < 4; ++h) {
            int i = v*4 + h;
            float xv = x4[h];
#pragma unroll
            for (int j = 0; j < C1; ++j) acc[j] += xv * W[i*C1+j];
        }
    }
    float dk = 0.f, dq = 0.f;
#pragma unroll
    for (int j = 0; j < C1; ++j) { dk += acc[j]*KV[j]; dq += acc[j]*QV[j]; }
    __half* o = xs1h + ((size_t)node * C1) * 2 + b;   // half2[node][c], comp b
#pragma unroll
    for (int j = 0; j < C1; ++j) o[2*j] = __float2half_rn(acc[j]);
    dotk1[node*2 + b] = dk; dotq1[node*2 + b] = dq;
}

// ---------------- edge layer 1: 16 lanes/edge, one pk-f16 atomic each --------
__global__ __launch_bounds__(256) void k_edge1(
        const int* __restrict__ ei, const float* __restrict__ ew,
        const float* __restrict__ we, const float* __restrict__ ab,
        const float* __restrict__ combo,
        const __half2* __restrict__ xsh, const float* __restrict__ dotk,
        const float* __restrict__ dotq, __half2* __restrict__ aggr) {
    int t = blockIdx.x * 256 + threadIdx.x;
    int e = t >> 4;
    int c = t & 15;
    if (e >= EE) return;
    int src = ei[e];
    int dst = ei[EE + e];
    float ef    = ew[e];
    float sig_e = sigmoidf(ef * we[c]);
    float eb    = ef * combo[96] + ab[0];
    float2 dq = *(const float2*)(dotq + src*2);
    float2 dk = *(const float2*)(dotk + dst*2);
    float2 xj = __half22float2(xsh[(size_t)src*C1 + c]);
    float m0 = sigmoidf(dk.x + dq.x + eb) * xj.x * sig_e;
    float m1 = sigmoidf(dk.y + dq.y + eb) * xj.y * sig_e;
    atomic_pk_add_f16(const_cast<__half2*>(aggr) + (size_t)dst*C1 + c,
                      __float22half2_rn(make_float2(m0, m1)));
}

// ---------------- fused: update1 + leaky_relu + xs2 = X1 @ value2 ------------
__global__ __launch_bounds__(256) void k_update1(
        const float* __restrict__ cat_w, const float* __restrict__ cat_b,
        const float* __restrict__ value2, const float* __restrict__ combo,
        const __half* __restrict__ xs1h, const __half* __restrict__ aggr1h,
        __half* __restrict__ xs2h, float* __restrict__ dotk2, float* __restrict__ dotq2) {
    __shared__ float CW[2*C1*C1];
    __shared__ float CB[C1];
    __shared__ float V2[C1*C2];
    __shared__ float KV[C2], QV[C2];
    int tid = threadIdx.x;
    for (int i = tid; i < 2*C1*C1; i += 256) CW[i] = cat_w[i];
    for (int i = tid; i < C1*C2;   i += 256) V2[i] = value2[i];
    if (tid < C1) CB[tid] = cat_b[tid];
    if (tid < C2) { KV[tid] = combo[32+tid]; QV[tid] = combo[64+tid]; }
    __syncthreads();
    int bn = blockIdx.x * 256 + tid;
    if (bn >= NB) return;
    int b = (bn >= NN) ? 1 : 0;
    int node = bn - b*NN;
    const __half* xr = xs1h   + ((size_t)node*C1)*2 + b;
    const __half* ar = aggr1h + ((size_t)node*C1)*2 + b;
    float xd[C1], ag[C1];
#pragma unroll
    for (int i = 0; i < C1; ++i) {
        xd[i] = __half2float(xr[2*i]);
        ag[i] = __half2float(ar[2*i]);
    }
    float x1[C1];
#pragma unroll
    for (int j = 0; j < C1; ++j) {
        float u = CB[j];
#pragma unroll
        for (int i = 0; i < C1; ++i) {
            u += xd[i] * CW[i*C1 + j];
            u += ag[i] * CW[(C1+i)*C1 + j];
        }
        float o = xd[j] + fmaxf(u, 0.f);
        x1[j] = (o > 0.f) ? o : 0.01f * o;       // leaky_relu
    }
    float o2[C2];
#pragma unroll
    for (int k = 0; k < C2; ++k) o2[k] = 0.f;
#pragma unroll
    for (int j = 0; j < C1; ++j) {
        float xv = x1[j];
#pragma unroll
        for (int k = 0; k < C2; ++k) o2[k] += xv * V2[j*C2 + k];
    }
    float dk = 0.f, dq = 0.f;
#pragma unroll
    for (int k = 0; k < C2; ++k) { dk += o2[k]*KV[k]; dq += o2[k]*QV[k]; }
    __half* o = xs2h + ((size_t)node*C2)*2 + b;
#pragma unroll
    for (int k = 0; k < C2; ++k) o[2*k] = __float2half_rn(o2[k]);
    dotk2[node*2 + b] = dk; dotq2[node*2 + b] = dq;
}

// ---------------- edge layer 2: 32 lanes/edge, one pk-f16 atomic each --------
__global__ __launch_bounds__(256) void k_edge2(
        const int* __restrict__ ei, const float* __restrict__ ew,
        const float* __restrict__ we, const float* __restrict__ ab,
        const float* __restrict__ combo,
        const __half2* __restrict__ xsh, const float* __restrict__ dotk,
        const float* __restrict__ dotq, __half2* __restrict__ aggr) {
    int t = blockIdx.x * 256 + threadIdx.x;
    int e = t >> 5;
    int c = t & 31;
    if (e >= EE) return;
    int src = ei[e];
    int dst = ei[EE + e];
    float ef    = ew[e];
    float sig_e = sigmoidf(ef * we[c]);
    float eb    = ef * combo[97] + ab[0];
    float2 dq = *(const float2*)(dotq + src*2);
    float2 dk = *(const float2*)(dotk + dst*2);
    float2 xj = __half22float2(xsh[(size_t)src*C2 + c]);
    float m0 = sigmoidf(dk.x + dq.x + eb) * xj.x * sig_e;
    float m1 = sigmoidf(dk.y + dq.y + eb) * xj.y * sig_e;
    atomic_pk_add_f16(const_cast<__half2*>(aggr) + (size_t)dst*C2 + c,
                      __float22half2_rn(make_float2(m0, m1)));
}

// ---------------- final: update2 -> fp32 out [b][node][c] --------------------
__global__ __launch_bounds__(256) void k_update2(
        const float* __restrict__ cat_w, const float* __restrict__ cat_b,
        const __half* __restrict__ xs2h, const __half* __restrict__ aggr2h,
        float* __restrict__ out) {
    __shared__ float CW[2*C2*C2];
    __shared__ float CB[C2];
    int tid = threadIdx.x;
    for (int i = tid; i < 2*C2*C2; i += 256) CW[i] = cat_w[i];
    if (tid < C2) CB[tid] = cat_b[tid];
    __syncthreads();
    int bn = blockIdx.x * 256 + tid;
    if (bn >= NB) return;
    int b = (bn >= NN) ? 1 : 0;
    int node = bn - b*NN;
    const __half* xr = xs2h   + ((size_t)node*C2)*2 + b;
    const __half* ar = aggr2h + ((size_t)node*C2)*2 + b;
    float xd[C2], ag[C2];
#pragma unroll
    for (int i = 0; i < C2; ++i) {
        xd[i] = __half2float(xr[2*i]);
        ag[i] = __half2float(ar[2*i]);
    }
    float o[C2];
#pragma unroll
    for (int k = 0; k < C2; ++k) {
        float u = CB[k];
#pragma unroll
        for (int i = 0; i < C2; ++i) {
            u += xd[i] * CW[i*C2 + k];
            u += ag[i] * CW[(C2+i)*C2 + k];
        }
        o[k] = xd[k] + fmaxf(u, 0.f);
    }
    float4* dst = (float4*)(out + (size_t)bn * C2);
#pragma unroll
    for (int v = 0; v < 8; ++v)
        dst[v] = make_float4(o[4*v], o[4*v+1], o[4*v+2], o[4*v+3]);
}

extern "C" void kernel_launch(void* const* d_in, const int* in_sizes, int n_in,
                              void* d_out, int out_size, void* d_ws, size_t ws_size,
                              hipStream_t stream) {
    const float* X      = (const float*)d_in[0];
    const int*   ei0    = (const int*)d_in[1];
    const int*   ei1    = (const int*)d_in[2];
    const float* ew0    = (const float*)d_in[3];
    const float* ew1    = (const float*)d_in[4];
    // d_in[5], d_in[6]: res_n_id0/1 == arange(N) -> identity gather, unused
    const float* value1 = (const float*)d_in[7];
    const float* key1   = (const float*)d_in[8];
    const float* query1 = (const float*)d_in[9];
    const float* we1    = (const float*)d_in[10];
    const float* aw1    = (const float*)d_in[11];
    const float* ab1    = (const float*)d_in[12];
    const float* cw1    = (const float*)d_in[13];
    const float* cb1    = (const float*)d_in[14];
    const float* value2 = (const float*)d_in[15];
    const float* key2   = (const float*)d_in[16];
    const float* query2 = (const float*)d_in[17];
    const float* we2    = (const float*)d_in[18];
    const float* aw2    = (const float*)d_in[19];
    const float* ab2    = (const float*)d_in[20];
    const float* cw2    = (const float*)d_in[21];
    const float* cb2    = (const float*)d_in[22];
    float* ws  = (float*)d_ws;
    float* out = (float*)d_out;

    __half*  xs1h   = (__half*)(ws + OFF_XS1);
    __half*  xs2h   = (__half*)(ws + OFF_XS2);
    __half2* aggr1h = (__half2*)(ws + OFF_AGGR1);
    __half2* aggr2h = (__half2*)(ws + OFF_AGGR2);

    // zero AGGR1+AGGR2 (contiguous region; half2 zero == bit zero)
    (void)hipMemsetAsync(ws + OFF_AGGR1, 0, (size_t)(NB*C1 + NB*C2) * sizeof(float), stream);

    k_combos<<<1, 64, 0, stream>>>(key1, query1, we1, aw1, key2, query2, we2, aw2,
                                   ws + OFF_COMBO);
    k_value1<<<(NB+255)/256, 256, 0, stream>>>(X, value1, ws + OFF_COMBO,
                                               xs1h, ws + OFF_DOTK1, ws + OFF_DOTQ1);
    k_edge1<<<(EE*16)/256, 256, 0, stream>>>(ei0, ew0, we1, ab1, ws + OFF_COMBO,
                                             (const __half2*)xs1h,
                                             ws + OFF_DOTK1, ws + OFF_DOTQ1, aggr1h);
    k_update1<<<(NB+255)/256, 256, 0, stream>>>(cw1, cb1, value2, ws + OFF_COMBO,
                                                xs1h, (const __half*)aggr1h,
                                                xs2h, ws + OFF_DOTK2, ws + OFF_DOTQ2);
    k_edge2<<<(EE*32)/256, 256, 0, stream>>>(ei1, ew1, we2, ab2, ws + OFF_COMBO,
                                             (const __half2*)xs2h,
                                             ws + OFF_DOTK2, ws + OFF_DOTQ2, aggr2h);
    k_update2<<<(NB+255)/256, 256, 0, stream>>>(cw2, cb2, xs2h, (const __half*)aggr2h, out);
}

// Round 7
// 326.079 us; speedup vs baseline: 2.1959x; 1.0078x over previous
//
#include <hip/hip_runtime.h>
#include <hip/hip_fp16.h>

#define BB   2
#define NN   50000
#define EE   800000
#define INCH 64
#define C1   16
#define C2   32
#define NB   (BB*NN)

// workspace layout (float-unit offsets; regions sized generously as if f32).
// xs/aggr are __half2[node][c] with .x=batch0,.y=batch1. dot*[node][b] f32.
#define OFF_XS1   0
#define OFF_XS2   (OFF_XS1   + NB*C1)
#define OFF_AGGR1 (OFF_XS2   + NB*C2)
#define OFF_AGGR2 (OFF_AGGR1 + NB*C1)
#define OFF_DOTK1 (OFF_AGGR2 + NB*C2)
#define OFF_DOTQ1 (OFF_DOTK1 + NB)
#define OFF_DOTK2 (OFF_DOTQ1 + NB)
#define OFF_DOTQ2 (OFF_DOTK2 + NB)

__device__ __forceinline__ float sigmoidf(float x) {
    return 1.0f / (1.0f + __expf(-x));
}

// packed 2xfp16 atomic add, device scope (sc1), fire-and-forget.
__device__ __forceinline__ void atomic_pk_add_f16(__half2* addr, __half2 v) {
    unsigned int bits = *reinterpret_cast<unsigned int*>(&v);
    asm volatile("global_atomic_pk_add_f16 %0, %1, off sc1"
                 :: "v"(addr), "v"(bits) : "memory");
}

// ---------------- layer 1: zero aggr + xs1 = X @ value1 ----------------------
__global__ __launch_bounds__(256) void k_value1(
        const float* __restrict__ X, const float* __restrict__ value1,
        const float* __restrict__ key1, const float* __restrict__ query1,
        const float* __restrict__ aw1,
        float4* __restrict__ zero1, float4* __restrict__ zero2,
        __half* __restrict__ xs1h, float* __restrict__ dotk1, float* __restrict__ dotq1) {
    __shared__ float W[INCH*C1];
    __shared__ float KV[C1], QV[C1];
    int tid = threadIdx.x;
    for (int i = tid; i < INCH*C1; i += 256) W[i] = value1[i];
    if (tid < C1) {
        float kv = 0.f, qv = 0.f;
#pragma unroll
        for (int j = 0; j < C1; ++j) {
            kv += key1[tid*C1+j]   * aw1[j];
            qv += query1[tid*C1+j] * aw1[C1+j];
        }
        KV[tid] = kv; QV[tid] = qv;
    }
    // fold the aggr memset in here (stream order protects edge1)
    {
        int gid = blockIdx.x * 256 + tid;
        int gstride = gridDim.x * 256;
        const float4 z = make_float4(0.f, 0.f, 0.f, 0.f);
        for (int i = gid; i < NN*C1/4; i += gstride) zero1[i] = z;
        for (int i = gid; i < NN*C2/4; i += gstride) zero2[i] = z;
    }
    __syncthreads();
    int bn = blockIdx.x * 256 + tid;
    if (bn >= NB) return;
    int b = (bn >= NN) ? 1 : 0;
    int node = bn - b*NN;
    const float4* Xr = (const float4*)(X + (size_t)bn * INCH);
    float acc[C1];
#pragma unroll
    for (int j = 0; j < C1; ++j) acc[j] = 0.f;
#pragma unroll
    for (int v = 0; v < 16; ++v) {
        float4 p = Xr[v];
        float x4[4] = {p.x, p.y, p.z, p.w};
#pragma unroll
        for (int h = 0; h < 4; ++h) {
            int i = v*4 + h;
            float xv = x4[h];
#pragma unroll
            for (int j = 0; j < C1; ++j) acc[j] += xv * W[i*C1+j];
        }
    }
    float dk = 0.f, dq = 0.f;
#pragma unroll
    for (int j = 0; j < C1; ++j) { dk += acc[j]*KV[j]; dq += acc[j]*QV[j]; }
    __half* o = xs1h + ((size_t)node * C1) * 2 + b;   // half2[node][c], comp b
#pragma unroll
    for (int j = 0; j < C1; ++j) o[2*j] = __float2half_rn(acc[j]);
    dotk1[node*2 + b] = dk; dotq1[node*2 + b] = dq;
}

// ---------------- edge layer 1: 16 lanes/edge, one pk-f16 atomic each --------
__global__ __launch_bounds__(256) void k_edge1(
        const int* __restrict__ ei, const float* __restrict__ ew,
        const float* __restrict__ we, const float* __restrict__ aw,
        const float* __restrict__ ab,
        const __half2* __restrict__ xsh, const float* __restrict__ dotk,
        const float* __restrict__ dotq, __half2* __restrict__ aggr) {
    __shared__ float s_ec;
    if (threadIdx.x == 0) {
        float e1 = 0.f;
#pragma unroll
        for (int j = 0; j < C1; ++j) e1 += we[j] * aw[2*C1+j];
        s_ec = e1;
    }
    __syncthreads();
    int t = blockIdx.x * 256 + threadIdx.x;
    int e = t >> 4;
    int c = t & 15;
    if (e >= EE) return;
    int src = ei[e];
    int dst = ei[EE + e];
    float ef    = ew[e];
    float sig_e = sigmoidf(ef * we[c]);
    float eb    = ef * s_ec + ab[0];
    float2 dq = *(const float2*)(dotq + src*2);
    float2 dk = *(const float2*)(dotk + dst*2);
    float2 xj = __half22float2(xsh[(size_t)src*C1 + c]);
    float m0 = sigmoidf(dk.x + dq.x + eb) * xj.x * sig_e;
    float m1 = sigmoidf(dk.y + dq.y + eb) * xj.y * sig_e;
    atomic_pk_add_f16(const_cast<__half2*>(aggr) + (size_t)dst*C1 + c,
                      __float22half2_rn(make_float2(m0, m1)));
}

// ---------------- fused: update1 + leaky_relu + xs2 = X1 @ value2 ------------
__global__ __launch_bounds__(256) void k_update1(
        const float* __restrict__ cat_w, const float* __restrict__ cat_b,
        const float* __restrict__ value2,
        const float* __restrict__ key2, const float* __restrict__ query2,
        const float* __restrict__ aw2,
        const __half* __restrict__ xs1h, const __half* __restrict__ aggr1h,
        __half* __restrict__ xs2h, float* __restrict__ dotk2, float* __restrict__ dotq2) {
    __shared__ float CW[2*C1*C1];
    __shared__ float CB[C1];
    __shared__ float V2[C1*C2];
    __shared__ float KV[C2], QV[C2];
    int tid = threadIdx.x;
    for (int i = tid; i < 2*C1*C1; i += 256) CW[i] = cat_w[i];
    for (int i = tid; i < C1*C2;   i += 256) V2[i] = value2[i];
    if (tid < C1) CB[tid] = cat_b[tid];
    if (tid < C2) {
        float kv = 0.f;
#pragma unroll
        for (int j = 0; j < C2; ++j) kv += key2[tid*C2+j] * aw2[j];
        KV[tid] = kv;
    } else if (tid < 2*C2) {
        int c = tid - C2;
        float qv = 0.f;
#pragma unroll
        for (int j = 0; j < C2; ++j) qv += query2[c*C2+j] * aw2[C2+j];
        QV[c] = qv;
    }
    __syncthreads();
    int bn = blockIdx.x * 256 + tid;
    if (bn >= NB) return;
    int b = (bn >= NN) ? 1 : 0;
    int node = bn - b*NN;
    const __half* xr = xs1h   + ((size_t)node*C1)*2 + b;
    const __half* ar = aggr1h + ((size_t)node*C1)*2 + b;
    float xd[C1], ag[C1];
#pragma unroll
    for (int i = 0; i < C1; ++i) {
        xd[i] = __half2float(xr[2*i]);
        ag[i] = __half2float(ar[2*i]);
    }
    float x1[C1];
#pragma unroll
    for (int j = 0; j < C1; ++j) {
        float u = CB[j];
#pragma unroll
        for (int i = 0; i < C1; ++i) {
            u += xd[i] * CW[i*C1 + j];
            u += ag[i] * CW[(C1+i)*C1 + j];
        }
        float o = xd[j] + fmaxf(u, 0.f);
        x1[j] = (o > 0.f) ? o : 0.01f * o;       // leaky_relu
    }
    float o2[C2];
#pragma unroll
    for (int k = 0; k < C2; ++k) o2[k] = 0.f;
#pragma unroll
    for (int j = 0; j < C1; ++j) {
        float xv = x1[j];
#pragma unroll
        for (int k = 0; k < C2; ++k) o2[k] += xv * V2[j*C2 + k];
    }
    float dk = 0.f, dq = 0.f;
#pragma unroll
    for (int k = 0; k < C2; ++k) { dk += o2[k]*KV[k]; dq += o2[k]*QV[k]; }
    __half* o = xs2h + ((size_t)node*C2)*2 + b;
#pragma unroll
    for (int k = 0; k < C2; ++k) o[2*k] = __float2half_rn(o2[k]);
    dotk2[node*2 + b] = dk; dotq2[node*2 + b] = dq;
}

// ---------------- edge layer 2: 32 lanes/edge, one pk-f16 atomic each --------
__global__ __launch_bounds__(256) void k_edge2(
        const int* __restrict__ ei, const float* __restrict__ ew,
        const float* __restrict__ we, const float* __restrict__ aw,
        const float* __restrict__ ab,
        const __half2* __restrict__ xsh, const float* __restrict__ dotk,
        const float* __restrict__ dotq, __half2* __restrict__ aggr) {
    __shared__ float s_ec;
    if (threadIdx.x == 0) {
        float e2 = 0.f;
#pragma unroll
        for (int j = 0; j < C2; ++j) e2 += we[j] * aw[2*C2+j];
        s_ec = e2;
    }
    __syncthreads();
    int t = blockIdx.x * 256 + threadIdx.x;
    int e = t >> 5;
    int c = t & 31;
    if (e >= EE) return;
    int src = ei[e];
    int dst = ei[EE + e];
    float ef    = ew[e];
    float sig_e = sigmoidf(ef * we[c]);
    float eb    = ef * s_ec + ab[0];
    float2 dq = *(const float2*)(dotq + src*2);
    float2 dk = *(const float2*)(dotk + dst*2);
    float2 xj = __half22float2(xsh[(size_t)src*C2 + c]);
    float m0 = sigmoidf(dk.x + dq.x + eb) * xj.x * sig_e;
    float m1 = sigmoidf(dk.y + dq.y + eb) * xj.y * sig_e;
    atomic_pk_add_f16(const_cast<__half2*>(aggr) + (size_t)dst*C2 + c,
                      __float22half2_rn(make_float2(m0, m1)));
}

// ---------------- final: update2 -> fp32 out [b][node][c] --------------------
__global__ __launch_bounds__(256) void k_update2(
        const float* __restrict__ cat_w, const float* __restrict__ cat_b,
        const __half* __restrict__ xs2h, const __half* __restrict__ aggr2h,
        float* __restrict__ out) {
    __shared__ float CW[2*C2*C2];
    __shared__ float CB[C2];
    int tid = threadIdx.x;
    for (int i = tid; i < 2*C2*C2; i += 256) CW[i] = cat_w[i];
    if (tid < C2) CB[tid] = cat_b[tid];
    __syncthreads();
    int bn = blockIdx.x * 256 + tid;
    if (bn >= NB) return;
    int b = (bn >= NN) ? 1 : 0;
    int node = bn - b*NN;
    const __half* xr = xs2h   + ((size_t)node*C2)*2 + b;
    const __half* ar = aggr2h + ((size_t)node*C2)*2 + b;
    float xd[C2], ag[C2];
#pragma unroll
    for (int i = 0; i < C2; ++i) {
        xd[i] = __half2float(xr[2*i]);
        ag[i] = __half2float(ar[2*i]);
    }
    float o[C2];
#pragma unroll
    for (int k = 0; k < C2; ++k) {
        float u = CB[k];
#pragma unroll
        for (int i = 0; i < C2; ++i) {
            u += xd[i] * CW[i*C2 + k];
            u += ag[i] * CW[(C2+i)*C2 + k];
        }
        o[k] = xd[k] + fmaxf(u, 0.f);
    }
    float4* dst = (float4*)(out + (size_t)bn * C2);
#pragma unroll
    for (int v = 0; v < 8; ++v)
        dst[v] = make_float4(o[4*v], o[4*v+1], o[4*v+2], o[4*v+3]);
}

extern "C" void kernel_launch(void* const* d_in, const int* in_sizes, int n_in,
                              void* d_out, int out_size, void* d_ws, size_t ws_size,
                              hipStream_t stream) {
    const float* X      = (const float*)d_in[0];
    const int*   ei0    = (const int*)d_in[1];
    const int*   ei1    = (const int*)d_in[2];
    const float* ew0    = (const float*)d_in[3];
    const float* ew1    = (const float*)d_in[4];
    // d_in[5], d_in[6]: res_n_id0/1 == arange(N) -> identity gather, unused
    const float* value1 = (const float*)d_in[7];
    const float* key1   = (const float*)d_in[8];
    const float* query1 = (const float*)d_in[9];
    const float* we1    = (const float*)d_in[10];
    const float* aw1    = (const float*)d_in[11];
    const float* ab1    = (const float*)d_in[12];
    const float* cw1    = (const float*)d_in[13];
    const float* cb1    = (const float*)d_in[14];
    const float* value2 = (const float*)d_in[15];
    const float* key2   = (const float*)d_in[16];
    const float* query2 = (const float*)d_in[17];
    const float* we2    = (const float*)d_in[18];
    const float* aw2    = (const float*)d_in[19];
    const float* ab2    = (const float*)d_in[20];
    const float* cw2    = (const float*)d_in[21];
    const float* cb2    = (const float*)d_in[22];
    float* ws  = (float*)d_ws;
    float* out = (float*)d_out;

    __half*  xs1h   = (__half*)(ws + OFF_XS1);
    __half*  xs2h   = (__half*)(ws + OFF_XS2);
    __half2* aggr1h = (__half2*)(ws + OFF_AGGR1);
    __half2* aggr2h = (__half2*)(ws + OFF_AGGR2);

    k_value1<<<(NB+255)/256, 256, 0, stream>>>(X, value1, key1, query1, aw1,
                                               (float4*)(ws + OFF_AGGR1),
                                               (float4*)(ws + OFF_AGGR2),
                                               xs1h, ws + OFF_DOTK1, ws + OFF_DOTQ1);
    k_edge1<<<(EE*16)/256, 256, 0, stream>>>(ei0, ew0, we1, aw1, ab1,
                                             (const __half2*)xs1h,
                                             ws + OFF_DOTK1, ws + OFF_DOTQ1, aggr1h);
    k_update1<<<(NB+255)/256, 256, 0, stream>>>(cw1, cb1, value2, key2, query2, aw2,
                                                xs1h, (const __half*)aggr1h,
                                                xs2h, ws + OFF_DOTK2, ws + OFF_DOTQ2);
    k_edge2<<<(EE*32)/256, 256, 0, stream>>>(ei1, ew1, we2, aw2, ab2,
                                             (const __half2*)xs2h,
                                             ws + OFF_DOTK2, ws + OFF_DOTQ2, aggr2h);
    k_update2<<<(NB+255)/256, 256, 0, stream>>>(cw2, cb2, xs2h, (const __half*)aggr2h, out);
}

// Round 8
// 302.094 us; speedup vs baseline: 2.3702x; 1.0794x over previous
//
#include <hip/hip_runtime.h>
#include <hip/hip_fp16.h>

#define BB   2
#define NN   50000
#define EE   800000
#define INCH 64
#define C1   16
#define C2   32
#define NB   (BB*NN)

#define SCALE     128.0f
#define INV_SCALE (1.0f/128.0f)

// workspace layout (float-unit offsets).
// xs1h/xs2h: half[node][c][b] (unit = c*2+b). aggr q-arrays: u64[node][c/2],
// each u64 = 4x16-bit fixed-point digits (c,b0),(c,b1),(c+1,b0),(c+1,b1).
#define OFF_XS1   0
#define OFF_XS2   (OFF_XS1 + NB*C1)
#define OFF_Q1    (OFF_XS2 + NB*C2)        // NN*8 u64  = NN*16 floats
#define OFF_Q2    (OFF_Q1  + NN*16)        // NN*16 u64 = NN*32 floats
#define OFF_DOTK1 (OFF_Q2  + NN*32)
#define OFF_DOTQ1 (OFF_DOTK1 + NB)
#define OFF_DOTK2 (OFF_DOTQ1 + NB)
#define OFF_DOTQ2 (OFF_DOTK2 + NB)
#define OFF_SC    (OFF_DOTQ2 + NB)         // sc[0]=ec1, sc[1]=ec2

__device__ __forceinline__ float sigmoidf(float x) {
    return 1.0f / (1.0f + __expf(-x));
}

// decode 4 signed base-2^16 digits from an exact i64 multiprecision sum.
__device__ __forceinline__ void decode4(long long u, float* s) {
    int d0 = (int)(short)(u & 0xffff); u = (u - d0) >> 16;
    int d1 = (int)(short)(u & 0xffff); u = (u - d1) >> 16;
    int d2 = (int)(short)(u & 0xffff); u = (u - d2) >> 16;
    int d3 = (int)u;
    s[0] = d0 * INV_SCALE; s[1] = d1 * INV_SCALE;
    s[2] = d2 * INV_SCALE; s[3] = d3 * INV_SCALE;
}

// ---------------- tiny scalar precompute -------------------------------------
__global__ void k_sc(const float* __restrict__ we1, const float* __restrict__ aw1,
                     const float* __restrict__ we2, const float* __restrict__ aw2,
                     float* __restrict__ sc) {
    if (threadIdx.x == 0) {
        float e = 0.f;
        for (int j = 0; j < C1; ++j) e += we1[j] * aw1[2*C1+j];
        sc[0] = e;
    }
    if (threadIdx.x == 1) {
        float e = 0.f;
        for (int j = 0; j < C2; ++j) e += we2[j] * aw2[2*C2+j];
        sc[1] = e;
    }
}

// ---------------- layer 1: xs1 = X @ value1 (half-packed out) ----------------
__global__ __launch_bounds__(256) void k_value1(
        const float* __restrict__ X, const float* __restrict__ value1,
        const float* __restrict__ key1, const float* __restrict__ query1,
        const float* __restrict__ aw1,
        __half* __restrict__ xs1h, float* __restrict__ dotk1, float* __restrict__ dotq1) {
    __shared__ float W[INCH*C1];
    __shared__ float KV[C1], QV[C1];
    int tid = threadIdx.x;
    for (int i = tid; i < INCH*C1; i += 256) W[i] = value1[i];
    if (tid < C1) {
        float kv = 0.f, qv = 0.f;
#pragma unroll
        for (int j = 0; j < C1; ++j) {
            kv += key1[tid*C1+j]   * aw1[j];
            qv += query1[tid*C1+j] * aw1[C1+j];
        }
        KV[tid] = kv; QV[tid] = qv;
    }
    __syncthreads();
    int bn = blockIdx.x * 256 + tid;
    if (bn >= NB) return;
    int b = (bn >= NN) ? 1 : 0;
    int node = bn - b*NN;
    const float4* Xr = (const float4*)(X + (size_t)bn * INCH);
    float acc[C1];
#pragma unroll
    for (int j = 0; j < C1; ++j) acc[j] = 0.f;
#pragma unroll
    for (int v = 0; v < 16; ++v) {
        float4 p = Xr[v];
        float x4[4] = {p.x, p.y, p.z, p.w};
#pragma unroll
        for (int h = 0; h < 4; ++h) {
            int i = v*4 + h;
            float xv = x4[h];
#pragma unroll
            for (int j = 0; j < C1; ++j) acc[j] += xv * W[i*C1+j];
        }
    }
    float dk = 0.f, dq = 0.f;
#pragma unroll
    for (int j = 0; j < C1; ++j) { dk += acc[j]*KV[j]; dq += acc[j]*QV[j]; }
    __half* o = xs1h + ((size_t)node * C1) * 2 + b;
#pragma unroll
    for (int j = 0; j < C1; ++j) o[2*j] = __float2half_rn(acc[j]);
    dotk1[node*2 + b] = dk; dotq1[node*2 + b] = dq;
}

// ---------------- edge layer 1: 8 lanes/edge, one u64 atomic each ------------
__global__ __launch_bounds__(256) void k_edge1(
        const int* __restrict__ ei, const float* __restrict__ ew,
        const float* __restrict__ we, const float* __restrict__ ab,
        const float* __restrict__ sc,
        const uint2* __restrict__ xsh, const float* __restrict__ dotk,
        const float* __restrict__ dotq, unsigned long long* __restrict__ aggr) {
    int t = blockIdx.x * 256 + threadIdx.x;
    int e = t >> 3;
    int cp = t & 7;
    if (e >= EE) return;
    int src = ei[e];
    int dst = ei[EE + e];
    float ef = ew[e];
    int c0 = cp * 2;
    float se0 = sigmoidf(ef * we[c0]);
    float se1 = sigmoidf(ef * we[c0+1]);
    float eb  = ef * sc[0] + ab[0];
    float2 dq = *(const float2*)(dotq + src*2);
    float2 dk = *(const float2*)(dotk + dst*2);
    float a0 = sigmoidf(dk.x + dq.x + eb);
    float a1 = sigmoidf(dk.y + dq.y + eb);
    uint2 xr = xsh[(size_t)src*8 + cp];
    float2 f0 = __half22float2(__builtin_bit_cast(__half2, xr.x));
    float2 f1 = __half22float2(__builtin_bit_cast(__half2, xr.y));
    int r0 = __float2int_rn(a0 * se0 * f0.x * SCALE);
    int r1 = __float2int_rn(a1 * se0 * f0.y * SCALE);
    int r2 = __float2int_rn(a0 * se1 * f1.x * SCALE);
    int r3 = __float2int_rn(a1 * se1 * f1.y * SCALE);
    long long pack = (long long)r0 + ((long long)r1 << 16)
                   + ((long long)r2 << 32) + ((long long)r3 << 48);
    atomicAdd(aggr + (size_t)dst*8 + cp, (unsigned long long)pack);
}

// ---------------- fused: update1 + leaky_relu + xs2 = X1 @ value2 ------------
__global__ __launch_bounds__(256) void k_update1(
        const float* __restrict__ cat_w, const float* __restrict__ cat_b,
        const float* __restrict__ value2,
        const float* __restrict__ key2, const float* __restrict__ query2,
        const float* __restrict__ aw2,
        const __half* __restrict__ xs1h, const unsigned long long* __restrict__ aggr1q,
        __half* __restrict__ xs2h, float* __restrict__ dotk2, float* __restrict__ dotq2) {
    __shared__ float CW[2*C1*C1];
    __shared__ float CB[C1];
    __shared__ float V2[C1*C2];
    __shared__ float KV[C2], QV[C2];
    int tid = threadIdx.x;
    for (int i = tid; i < 2*C1*C1; i += 256) CW[i] = cat_w[i];
    for (int i = tid; i < C1*C2;   i += 256) V2[i] = value2[i];
    if (tid < C1) CB[tid] = cat_b[tid];
    if (tid < C2) {
        float kv = 0.f;
#pragma unroll
        for (int j = 0; j < C2; ++j) kv += key2[tid*C2+j] * aw2[j];
        KV[tid] = kv;
    } else if (tid < 2*C2) {
        int c = tid - C2;
        float qv = 0.f;
#pragma unroll
        for (int j = 0; j < C2; ++j) qv += query2[c*C2+j] * aw2[C2+j];
        QV[c] = qv;
    }
    __syncthreads();
    int bn = blockIdx.x * 256 + tid;
    if (bn >= NB) return;
    int b = (bn >= NN) ? 1 : 0;
    int node = bn - b*NN;
    const __half* xr = xs1h + ((size_t)node*C1)*2 + b;
    const long long* q = (const long long*)(aggr1q + (size_t)node*8);
    float xd[C1], ag[C1];
#pragma unroll
    for (int i = 0; i < C1; ++i) xd[i] = __half2float(xr[2*i]);
#pragma unroll
    for (int i = 0; i < C1/2; ++i) {
        float s[4];
        decode4(q[i], s);
        ag[2*i]   = s[b];
        ag[2*i+1] = s[2+b];
    }
    float x1[C1];
#pragma unroll
    for (int j = 0; j < C1; ++j) {
        float u = CB[j];
#pragma unroll
        for (int i = 0; i < C1; ++i) {
            u += xd[i] * CW[i*C1 + j];
            u += ag[i] * CW[(C1+i)*C1 + j];
        }
        float o = xd[j] + fmaxf(u, 0.f);
        x1[j] = (o > 0.f) ? o : 0.01f * o;       // leaky_relu
    }
    float o2[C2];
#pragma unroll
    for (int k = 0; k < C2; ++k) o2[k] = 0.f;
#pragma unroll
    for (int j = 0; j < C1; ++j) {
        float xv = x1[j];
#pragma unroll
        for (int k = 0; k < C2; ++k) o2[k] += xv * V2[j*C2 + k];
    }
    float dk = 0.f, dq = 0.f;
#pragma unroll
    for (int k = 0; k < C2; ++k) { dk += o2[k]*KV[k]; dq += o2[k]*QV[k]; }
    __half* o = xs2h + ((size_t)node*C2)*2 + b;
#pragma unroll
    for (int k = 0; k < C2; ++k) o[2*k] = __float2half_rn(o2[k]);
    dotk2[node*2 + b] = dk; dotq2[node*2 + b] = dq;
}

// ---------------- edge layer 2: 16 lanes/edge, one u64 atomic each -----------
__global__ __launch_bounds__(256) void k_edge2(
        const int* __restrict__ ei, const float* __restrict__ ew,
        const float* __restrict__ we, const float* __restrict__ ab,
        const float* __restrict__ sc,
        const uint2* __restrict__ xsh, const float* __restrict__ dotk,
        const float* __restrict__ dotq, unsigned long long* __restrict__ aggr) {
    int t = blockIdx.x * 256 + threadIdx.x;
    int e = t >> 4;
    int cp = t & 15;
    if (e >= EE) return;
    int src = ei[e];
    int dst = ei[EE + e];
    float ef = ew[e];
    int c0 = cp * 2;
    float se0 = sigmoidf(ef * we[c0]);
    float se1 = sigmoidf(ef * we[c0+1]);
    float eb  = ef * sc[1] + ab[0];
    float2 dq = *(const float2*)(dotq + src*2);
    float2 dk = *(const float2*)(dotk + dst*2);
    float a0 = sigmoidf(dk.x + dq.x + eb);
    float a1 = sigmoidf(dk.y + dq.y + eb);
    uint2 xr = xsh[(size_t)src*16 + cp];
    float2 f0 = __half22float2(__builtin_bit_cast(__half2, xr.x));
    float2 f1 = __half22float2(__builtin_bit_cast(__half2, xr.y));
    int r0 = __float2int_rn(a0 * se0 * f0.x * SCALE);
    int r1 = __float2int_rn(a1 * se0 * f0.y * SCALE);
    int r2 = __float2int_rn(a0 * se1 * f1.x * SCALE);
    int r3 = __float2int_rn(a1 * se1 * f1.y * SCALE);
    long long pack = (long long)r0 + ((long long)r1 << 16)
                   + ((long long)r2 << 32) + ((long long)r3 << 48);
    atomicAdd(aggr + (size_t)dst*16 + cp, (unsigned long long)pack);
}

// ---------------- final: update2 -> fp32 out [b][node][c] --------------------
__global__ __launch_bounds__(256) void k_update2(
        const float* __restrict__ cat_w, const float* __restrict__ cat_b,
        const __half* __restrict__ xs2h, const unsigned long long* __restrict__ aggr2q,
        float* __restrict__ out) {
    __shared__ float CW[2*C2*C2];
    __shared__ float CB[C2];
    int tid = threadIdx.x;
    for (int i = tid; i < 2*C2*C2; i += 256) CW[i] = cat_w[i];
    if (tid < C2) CB[tid] = cat_b[tid];
    __syncthreads();
    int bn = blockIdx.x * 256 + tid;
    if (bn >= NB) return;
    int b = (bn >= NN) ? 1 : 0;
    int node = bn - b*NN;
    const __half* xr = xs2h + ((size_t)node*C2)*2 + b;
    const long long* q = (const long long*)(aggr2q + (size_t)node*16);
    float xd[C2], ag[C2];
#pragma unroll
    for (int i = 0; i < C2; ++i) xd[i] = __half2float(xr[2*i]);
#pragma unroll
    for (int i = 0; i < C2/2; ++i) {
        float s[4];
        decode4(q[i], s);
        ag[2*i]   = s[b];
        ag[2*i+1] = s[2+b];
    }
    float o[C2];
#pragma unroll
    for (int k = 0; k < C2; ++k) {
        float u = CB[k];
#pragma unroll
        for (int i = 0; i < C2; ++i) {
            u += xd[i] * CW[i*C2 + k];
            u += ag[i] * CW[(C2+i)*C2 + k];
        }
        o[k] = xd[k] + fmaxf(u, 0.f);
    }
    float4* dst = (float4*)(out + (size_t)bn * C2);
#pragma unroll
    for (int v = 0; v < 8; ++v)
        dst[v] = make_float4(o[4*v], o[4*v+1], o[4*v+2], o[4*v+3]);
}

extern "C" void kernel_launch(void* const* d_in, const int* in_sizes, int n_in,
                              void* d_out, int out_size, void* d_ws, size_t ws_size,
                              hipStream_t stream) {
    const float* X      = (const float*)d_in[0];
    const int*   ei0    = (const int*)d_in[1];
    const int*   ei1    = (const int*)d_in[2];
    const float* ew0    = (const float*)d_in[3];
    const float* ew1    = (const float*)d_in[4];
    // d_in[5], d_in[6]: res_n_id0/1 == arange(N) -> identity gather, unused
    const float* value1 = (const float*)d_in[7];
    const float* key1   = (const float*)d_in[8];
    const float* query1 = (const float*)d_in[9];
    const float* we1    = (const float*)d_in[10];
    const float* aw1    = (const float*)d_in[11];
    const float* ab1    = (const float*)d_in[12];
    const float* cw1    = (const float*)d_in[13];
    const float* cb1    = (const float*)d_in[14];
    const float* value2 = (const float*)d_in[15];
    const float* key2   = (const float*)d_in[16];
    const float* query2 = (const float*)d_in[17];
    const float* we2    = (const float*)d_in[18];
    const float* aw2    = (const float*)d_in[19];
    const float* ab2    = (const float*)d_in[20];
    const float* cw2    = (const float*)d_in[21];
    const float* cb2    = (const float*)d_in[22];
    float* ws  = (float*)d_ws;
    float* out = (float*)d_out;

    __half* xs1h = (__half*)(ws + OFF_XS1);
    __half* xs2h = (__half*)(ws + OFF_XS2);
    unsigned long long* aggr1q = (unsigned long long*)(ws + OFF_Q1);
    unsigned long long* aggr2q = (unsigned long long*)(ws + OFF_Q2);

    // zero both q-accumulators (contiguous, 9.6 MB)
    (void)hipMemsetAsync(ws + OFF_Q1, 0, (size_t)(NN*16 + NN*32) * sizeof(float), stream);

    k_sc<<<1, 64, 0, stream>>>(we1, aw1, we2, aw2, ws + OFF_SC);
    k_value1<<<(NB+255)/256, 256, 0, stream>>>(X, value1, key1, query1, aw1,
                                               xs1h, ws + OFF_DOTK1, ws + OFF_DOTQ1);
    k_edge1<<<(EE*8)/256, 256, 0, stream>>>(ei0, ew0, we1, ab1, ws + OFF_SC,
                                            (const uint2*)xs1h,
                                            ws + OFF_DOTK1, ws + OFF_DOTQ1, aggr1q);
    k_update1<<<(NB+255)/256, 256, 0, stream>>>(cw1, cb1, value2, key2, query2, aw2,
                                                xs1h, aggr1q,
                                                xs2h, ws + OFF_DOTK2, ws + OFF_DOTQ2);
    k_edge2<<<(EE*16)/256, 256, 0, stream>>>(ei1, ew1, we2, ab2, ws + OFF_SC,
                                             (const uint2*)xs2h,
                                             ws + OFF_DOTK2, ws + OFF_DOTQ2, aggr2q);
    k_update2<<<(NB+255)/256, 256, 0, stream>>>(cw2, cb2, xs2h, aggr2q, out);
}